// Round 12
// baseline (118.349 us; speedup 1.0000x reference)
//
#include <hip/hip_runtime.h>
#include <hip/hip_bf16.h>

// Problem constants: B=8, N=8192, S=2048, C1=128, C2=256, OUT=256
#define BB   8
#define NN   8192
#define SS   2048
#define C1C  128
#define C2C  256
#define KIN  384
#define OUTC 256

typedef __attribute__((ext_vector_type(4))) float f32x4;
typedef __attribute__((ext_vector_type(8))) short short8;
typedef __attribute__((ext_vector_type(8))) unsigned short ushortx8;

__device__ __forceinline__ ushort f2bf(float v) {
    __hip_bfloat16 h = __float2bfloat16(v);
    return __builtin_bit_cast(ushort, h);
}

__device__ __forceinline__ float med3(float a, float b, float c) {
    return __builtin_amdgcn_fmed3f(a, b, c);
}

// ---------------------------------------------------------------------------
// Fused 3-NN scan + gather (r11-measured 65.5us, VALU-issue-bound at max
// occupancy — UNCHANGED this round).
// L=16 lanes/query, Q=2 queries/thread, 128 queries/block, 1024 threads,
// grid 512 = 2 blocks/CU = 8 waves/SIMD. Two-pass: branchless med3 value
// pass -> exact 3rd-smallest threshold -> rare-insert index pass (lex
// (f,idx) == stable lax.top_k). Gather fused, coalesced 1KB feat2 rows.
// ---------------------------------------------------------------------------
__global__ __launch_bounds__(1024, 8) void knn_gather_kernel(
    const float* __restrict__ xyz1, const float* __restrict__ xyz2,
    const float* __restrict__ feat2, ushort* __restrict__ interpB)
{
    __shared__ float4 sp[SS];                     // 32 KB
    __shared__ int   sIdx[128][3];
    __shared__ float sW[128][3];

    const int tid   = threadIdx.x;
    const int b     = blockIdx.x & 7;             // XCD-aligned batch
    const int chunk = blockIdx.x >> 3;            // 0..63
    const int qbase = chunk << 7;                 // 128 queries per block

    const float* x2 = xyz2 + (size_t)b * SS * 3;
    for (int i = tid; i < SS; i += 1024) {
        float x = x2[i*3+0], y = x2[i*3+1], z = x2[i*3+2];
        sp[i] = make_float4(-2.f*x, -2.f*y, -2.f*z, x*x + y*y + z*z);
    }
    __syncthreads();

    const int g = tid >> 4;                       // 0..63 (query pair)
    const int l = tid & 15;                       // lane within query
    const int qa = qbase + g * 2;

    const float* qp = xyz1 + ((size_t)b * NN + qa) * 3;
    float px[2] = {qp[0], qp[3]};
    float py[2] = {qp[1], qp[4]};
    float pz[2] = {qp[2], qp[5]};

    // ---------------- pass 1: top-3 values, branchless ----------------
    float c0[2], c1[2], c2[2];
#pragma unroll
    for (int qi = 0; qi < 2; ++qi) { c0[qi] = c1[qi] = c2[qi] = 1e30f; }

    for (int jj = 0; jj < 128; jj += 4) {
        float4 P[4];
#pragma unroll
        for (int u = 0; u < 4; ++u) P[u] = sp[((jj + u) << 4) + l];
#pragma unroll
        for (int u = 0; u < 4; ++u) {
#pragma unroll
            for (int qi = 0; qi < 2; ++qi) {
                float f = fmaf(px[qi], P[u].x,
                          fmaf(py[qi], P[u].y,
                          fmaf(pz[qi], P[u].z, P[u].w)));
                c2[qi] = med3(f, c1[qi], c2[qi]);
                c1[qi] = med3(f, c0[qi], c1[qi]);
                c0[qi] = fminf(f, c0[qi]);
            }
        }
    }

    // value-merge across the 16-lane group (multiset union top-3)
#pragma unroll
    for (int m = 1; m <= 8; m <<= 1) {
#pragma unroll
        for (int qi = 0; qi < 2; ++qi) {
            float b0 = __shfl_xor(c0[qi], m);
            float b1 = __shfl_xor(c1[qi], m);
            float b2 = __shfl_xor(c2[qi], m);
            float bv[3] = {b0, b1, b2};
#pragma unroll
            for (int e = 0; e < 3; ++e) {
                float d = bv[e];
                c2[qi] = med3(d, c1[qi], c2[qi]);
                c1[qi] = med3(d, c0[qi], c1[qi]);
                c0[qi] = fminf(d, c0[qi]);
            }
        }
    }
    const float t0 = c2[0], t1 = c2[1];           // exact 3rd-smallest scores

    // ---------------- pass 2: index recovery (rare inserts) ----------------
    float e0[2], e1[2], e2[2];
    int   i0[2], i1[2], i2[2];
#pragma unroll
    for (int qi = 0; qi < 2; ++qi) {
        e0[qi] = e1[qi] = e2[qi] = 1e30f;
        i0[qi] = i1[qi] = i2[qi] = 0x3fffffff;
    }

    for (int jj = 0; jj < 128; jj += 4) {
        float4 P[4];
#pragma unroll
        for (int u = 0; u < 4; ++u) P[u] = sp[((jj + u) << 4) + l];
#pragma unroll
        for (int u = 0; u < 4; ++u) {
            const int s = ((jj + u) << 4) + l;
#pragma unroll
            for (int qi = 0; qi < 2; ++qi) {
                float f = fmaf(px[qi], P[u].x,
                          fmaf(py[qi], P[u].y,
                          fmaf(pz[qi], P[u].z, P[u].w)));
                float tq = qi ? t1 : t0;
                if (f <= tq) {                     // ~3 hits per query total
                    bool lt2 = (f < e2[qi]) || (f == e2[qi] && s < i2[qi]);
                    if (lt2) {
                        bool lt1 = (f < e1[qi]) || (f == e1[qi] && s < i1[qi]);
                        bool lt0 = (f < e0[qi]) || (f == e0[qi] && s < i0[qi]);
                        e2[qi] = lt1 ? e1[qi] : f;  i2[qi] = lt1 ? i1[qi] : s;
                        e1[qi] = lt0 ? e0[qi] : (lt1 ? f : e1[qi]);
                        i1[qi] = lt0 ? i0[qi] : (lt1 ? s : i1[qi]);
                        e0[qi] = lt0 ? f : e0[qi];  i0[qi] = lt0 ? s : i0[qi];
                    }
                }
            }
        }
    }

    // lex merge across the 16-lane group
#pragma unroll
    for (int m = 1; m <= 8; m <<= 1) {
#pragma unroll
        for (int qi = 0; qi < 2; ++qi) {
            float ob0 = __shfl_xor(e0[qi], m), ob1 = __shfl_xor(e1[qi], m), ob2 = __shfl_xor(e2[qi], m);
            int   oj0 = __shfl_xor(i0[qi], m), oj1 = __shfl_xor(i1[qi], m), oj2 = __shfl_xor(i2[qi], m);
            float dv[3] = {ob0, ob1, ob2}; int iv[3] = {oj0, oj1, oj2};
#pragma unroll
            for (int e = 0; e < 3; ++e) {
                float d = dv[e]; int s = iv[e];
                bool lt2 = (d < e2[qi]) || (d == e2[qi] && s < i2[qi]);
                if (lt2) {
                    bool lt1 = (d < e1[qi]) || (d == e1[qi] && s < i1[qi]);
                    bool lt0 = (d < e0[qi]) || (d == e0[qi] && s < i0[qi]);
                    e2[qi] = lt1 ? e1[qi] : d;  i2[qi] = lt1 ? i1[qi] : s;
                    e1[qi] = lt0 ? e0[qi] : (lt1 ? d : e1[qi]);
                    i1[qi] = lt0 ? i0[qi] : (lt1 ? s : i1[qi]);
                    e0[qi] = lt0 ? d : e0[qi];  i0[qi] = lt0 ? s : i0[qi];
                }
            }
        }
    }

    if (l == 0) {
#pragma unroll
        for (int qi = 0; qi < 2; ++qi) {
            float nx = px[qi], ny = py[qi], nz = pz[qi];
            float n1 = nx*nx + ny*ny + nz*nz;
            float d0 = sqrtf(fmaxf(n1 + e0[qi], 0.f));
            float d1 = sqrtf(fmaxf(n1 + e1[qi], 0.f));
            float d2s = sqrtf(fmaxf(n1 + e2[qi], 0.f));
            float w0 = 1.f / fmaxf(d0, 1e-10f);
            float w1 = 1.f / fmaxf(d1, 1e-10f);
            float w2 = 1.f / fmaxf(d2s, 1e-10f);
            float wsum = w0 + w1 + w2;
            int qq = g * 2 + qi;
            sIdx[qq][0] = i0[qi]; sIdx[qq][1] = i1[qi]; sIdx[qq][2] = i2[qi];
            sW[qq][0] = w0 / wsum; sW[qq][1] = w1 / wsum; sW[qq][2] = w2 / wsum;
        }
    }
    __syncthreads();

    // gather phase: wave wid handles queries wid, wid+16, ... (coalesced rows)
    const int wid = tid >> 6, lane = tid & 63;
    for (int qq = wid; qq < 128; qq += 16) {
        int a0 = sIdx[qq][0], a1 = sIdx[qq][1], a2 = sIdx[qq][2];
        float w0 = sW[qq][0], w1 = sW[qq][1], w2 = sW[qq][2];
        const float4* r0 = (const float4*)(feat2 + ((size_t)b * SS + a0) * C2C);
        const float4* r1 = (const float4*)(feat2 + ((size_t)b * SS + a1) * C2C);
        const float4* r2 = (const float4*)(feat2 + ((size_t)b * SS + a2) * C2C);
        float4 v0 = r0[lane], v1 = r1[lane], v2 = r2[lane];
        ushort4 o;
        o.x = f2bf(w0*v0.x + w1*v1.x + w2*v2.x);
        o.y = f2bf(w0*v0.y + w1*v1.y + w2*v2.y);
        o.z = f2bf(w0*v0.z + w1*v1.z + w2*v2.z);
        o.w = f2bf(w0*v0.w + w1*v1.w + w2*v2.w);
        *(ushort4*)(interpB + ((size_t)b * NN + qbase + qq) * C2C + lane * 4) = o;
    }
}

// ---------------------------------------------------------------------------
// Both weight transposes (W1: 384x256, W2: 256x256) in one launch.
// ---------------------------------------------------------------------------
__global__ __launch_bounds__(256) void transpose_cvt_both_kernel(
    const float* __restrict__ W1, ushort* __restrict__ W1t,
    const float* __restrict__ W2, ushort* __restrict__ W2t)
{
    int idx = blockIdx.x * 256 + threadIdx.x;
    const int n1 = KIN * OUTC;                    // 98304
    if (idx < n1) {
        int n = idx / KIN, k = idx - n * KIN;
        W1t[idx] = f2bf(W1[(size_t)k * OUTC + n]);
    } else {
        int j = idx - n1;
        if (j < OUTC * OUTC) {
            int n = j / OUTC, k = j - n * OUTC;
            W2t[j] = f2bf(W2[(size_t)k * OUTC + n]);
        }
    }
}

// ---------------------------------------------------------------------------
// FUSED two-layer MFMA GEMM, v2:
//   out = relu(relu(A@W1t^T + b1)@W2t^T + b2), H in LDS only.
// Changes vs r9/r11 (theory: W1t/W2t are 192/128KB = L2-resident and shared
// by all 512 blocks -> read B-fragments DIRECTLY from global into registers;
// LDS staging + its barriers were pure overhead):
//  - no sB/sB2; B frags via global short8 loads (L1/L2-hit under MFMA).
//  - sA double-buffered (2 x 8KB): ONE barrier per K-step (was 2); stage of
//    k+1 issued before compute of k (latency hidden; vmcnt drained at the
//    next barrier by the compiler).
//  - phase 2 entirely barrier-free (H read-only after one transition barrier).
// LDS: 16KB sA-dbuf + 64KB H pool = 80KB -> 2 blocks/CU unchanged.
// C/D mapping (verified r1+): col = lane&15, row = (lane>>4)*4 + reg.
// ---------------------------------------------------------------------------
#define GBM 128
#define GBN 256
#define GBK 32

__device__ __forceinline__ void gld_lds16(const void* g, void* l) {
    __builtin_amdgcn_global_load_lds(
        (const __attribute__((address_space(1))) void*)g,
        (__attribute__((address_space(3))) void*)l, 16, 0, 0);
}

__global__ __launch_bounds__(512, 4) void gemm_fused(
    const float* __restrict__ feat1,
    const ushort* __restrict__ interpB,
    const ushort* __restrict__ W1t, const float* __restrict__ b1,
    const ushort* __restrict__ W2t, const float* __restrict__ b2,
    float* __restrict__ out)
{
    __shared__ ushort sA[2 * GBM * GBK];   // 16 KB: double-buffered A K-slice
    __shared__ ushort pool[GBM * 256];     // 64 KB: H (phase 2 A-operand)

    const int tid  = threadIdx.x;
    const int lane = tid & 63;
    const int wid  = tid >> 6;           // 0..7
    const int m0   = blockIdx.x * GBM;
    const int wr   = wid >> 2;           // 0..1
    const int wc   = wid & 3;            // 0..3

    const int rsub = lane >> 2;                    // 0..15 (row in 16-row chunk)
    const int slot = lane & 3;                     // 0..3  (8-ushort slot)
    const int csub = slot * 8;                     // linear LDS slot offset
    const int usw  = (slot ^ (rsub & 3)) * 8;      // swizzled SOURCE slot offset

    const int kgrp = (lane >> 4) * 8;
    const int rl   = lane & 15;
    const int ksw  = kgrp ^ ((rl & 3) << 3);       // swizzled read slot
    const int cl   = lane & 15;
    const int rgrp = (lane >> 4) * 4;

    // stage this wave's 16-row A-chunk (chunk id == wid) for K-step k0
    auto stageA = [&](int k0, int buf) {
        ushort* dst = sA + buf * (GBM * GBK);
        const int r = m0 + wid * 16 + rsub;
        if (k0 < C1C) {
            const float* src = feat1 + (size_t)r * C1C + k0 + usw;
            float4 u = ((const float4*)src)[0];
            float4 v = ((const float4*)src)[1];
            ushortx8 t;
            t[0] = f2bf(u.x); t[1] = f2bf(u.y); t[2] = f2bf(u.z); t[3] = f2bf(u.w);
            t[4] = f2bf(v.x); t[5] = f2bf(v.y); t[6] = f2bf(v.z); t[7] = f2bf(v.w);
            *(ushortx8*)&dst[wid * 512 + rsub * 32 + csub] = t;
        } else {
            gld_lds16(interpB + (size_t)r * C2C + (k0 - C1C) + usw, &dst[wid * 512]);
        }
    };

    // ---------------- phase 1: acc1 = A @ W1t^T ----------------
    f32x4 acc1[4][4];
#pragma unroll
    for (int i = 0; i < 4; ++i)
#pragma unroll
        for (int j = 0; j < 4; ++j) acc1[i][j] = (f32x4){0.f, 0.f, 0.f, 0.f};

    int cur = 0;
    stageA(0, 0);
    for (int k0 = 0; k0 < KIN; k0 += GBK) {
        __syncthreads();                           // sA[cur] ready (vm/lgkm drained)
        if (k0 + GBK < KIN) stageA(k0 + GBK, cur ^ 1);

        short8 af[4], bf[4];
        const ushort* Wp = W1t + k0 + kgrp;
#pragma unroll
        for (int j = 0; j < 4; ++j)
            bf[j] = *(const short8*)&Wp[(size_t)(wc * 64 + j * 16 + rl) * KIN];
        const ushort* Ap = sA + cur * (GBM * GBK);
#pragma unroll
        for (int i = 0; i < 4; ++i)
            af[i] = *(const short8*)&Ap[(wr * 64 + i * 16 + rl) * GBK + ksw];

#pragma unroll
        for (int i = 0; i < 4; ++i)
#pragma unroll
            for (int j = 0; j < 4; ++j)
                acc1[i][j] = __builtin_amdgcn_mfma_f32_16x16x32_bf16(
                    af[i], bf[j], acc1[i][j], 0, 0, 0);
        cur ^= 1;
    }

    // ---------------- transition: H = relu(acc1+b1) -> LDS (bf16) ----------
#pragma unroll
    for (int j = 0; j < 4; ++j) {
        const int c = wc * 64 + j * 16 + cl;
        const float bv = b1[c];
        const int u = c >> 3, sub = c & 7;
#pragma unroll
        for (int i = 0; i < 4; ++i) {
#pragma unroll
            for (int rr = 0; rr < 4; ++rr) {
                const int r = wr * 64 + i * 16 + rgrp + rr;
                const float v = fmaxf(acc1[i][j][rr] + bv, 0.f);
                pool[r * 256 + ((u ^ (r & 31)) << 3) + sub] = f2bf(v);
            }
        }
    }
    __syncthreads();                               // H complete

    // ---------------- phase 2: out = relu(H @ W2t^T + b2), barrier-free ----
    f32x4 acc2[4][4];
#pragma unroll
    for (int i = 0; i < 4; ++i)
#pragma unroll
        for (int j = 0; j < 4; ++j) acc2[i][j] = (f32x4){0.f, 0.f, 0.f, 0.f};

    for (int k0 = 0; k0 < OUTC; k0 += GBK) {
        short8 af[4], bf[4];
        const ushort* Wp = W2t + k0 + kgrp;
#pragma unroll
        for (int j = 0; j < 4; ++j)
            bf[j] = *(const short8*)&Wp[(size_t)(wc * 64 + j * 16 + rl) * OUTC];
        const int ub = (k0 >> 3) + (lane >> 4);    // H unit index 0..31
#pragma unroll
        for (int i = 0; i < 4; ++i) {
            const int r = wr * 64 + i * 16 + rl;
            af[i] = *(const short8*)&pool[r * 256 + ((ub ^ (r & 31)) << 3)];
        }
#pragma unroll
        for (int i = 0; i < 4; ++i)
#pragma unroll
            for (int j = 0; j < 4; ++j)
                acc2[i][j] = __builtin_amdgcn_mfma_f32_16x16x32_bf16(
                    af[i], bf[j], acc2[i][j], 0, 0, 0);
    }

    // ---------------- epilogue: bias + relu -> f32 out ---------------------
#pragma unroll
    for (int j = 0; j < 4; ++j) {
        const int col = wc * 64 + j * 16 + cl;
        const float bv = b2[col];
#pragma unroll
        for (int i = 0; i < 4; ++i) {
            const int rowb = m0 + wr * 64 + i * 16 + rgrp;
#pragma unroll
            for (int rr = 0; rr < 4; ++rr) {
                out[(size_t)(rowb + rr) * OUTC + col] =
                    fmaxf(acc2[i][j][rr] + bv, 0.f);
            }
        }
    }
}

// ---------------------------------------------------------------------------
// ws layout (bytes): interpB 33.5M @0 | W1t @33554432 | W2t @33751040
// ---------------------------------------------------------------------------
extern "C" void kernel_launch(void* const* d_in, const int* in_sizes, int n_in,
                              void* d_out, int out_size, void* d_ws, size_t ws_size,
                              hipStream_t stream) {
    const float* xyz1  = (const float*)d_in[0];
    const float* xyz2  = (const float*)d_in[1];
    const float* feat1 = (const float*)d_in[2];
    const float* feat2 = (const float*)d_in[3];
    const float* W1    = (const float*)d_in[4];
    const float* b1    = (const float*)d_in[5];
    const float* W2    = (const float*)d_in[6];
    const float* b2    = (const float*)d_in[7];
    float* out = (float*)d_out;

    char* ws = (char*)d_ws;
    ushort* interpB = (ushort*)(ws);
    ushort* W1t     = (ushort*)(ws + 33554432);
    ushort* W2t     = (ushort*)(ws + 33751040);

    const int M = BB * NN;  // 65536

    transpose_cvt_both_kernel<<<(KIN * OUTC + OUTC * OUTC + 255) / 256, 256, 0, stream>>>(
        W1, W1t, W2, W2t);

    knn_gather_kernel<<<512, 1024, 0, stream>>>(xyz1, xyz2, feat2, interpB);

    gemm_fused<<<M / GBM, 512, 0, stream>>>(feat1, interpB, W1t, b1, W2t, b2, out);
}

// Round 13
// 110.608 us; speedup vs baseline: 1.0700x; 1.0700x over previous
//
#include <hip/hip_runtime.h>
#include <hip/hip_bf16.h>

// Problem constants: B=8, N=8192, S=2048, C1=128, C2=256, OUT=256
#define BB   8
#define NN   8192
#define SS   2048
#define C1C  128
#define C2C  256
#define KIN  384
#define OUTC 256

typedef __attribute__((ext_vector_type(4))) float f32x4;
typedef __attribute__((ext_vector_type(8))) short short8;
typedef __attribute__((ext_vector_type(8))) unsigned short ushortx8;

__device__ __forceinline__ ushort f2bf(float v) {
    __hip_bfloat16 h = __float2bfloat16(v);
    return __builtin_bit_cast(ushort, h);
}

__device__ __forceinline__ float med3(float a, float b, float c) {
    return __builtin_amdgcn_fmed3f(a, b, c);
}

// ---------------------------------------------------------------------------
// Fused 3-NN scan + gather (r11-measured 65.5us, VALU-issue-bound at max
// occupancy — UNCHANGED).
// L=16 lanes/query, Q=2 queries/thread, 128 queries/block, 1024 threads,
// grid 512 = 2 blocks/CU = 8 waves/SIMD. Two-pass: branchless med3 value
// pass -> exact 3rd-smallest threshold -> rare-insert index pass (lex
// (f,idx) == stable lax.top_k). Gather fused, coalesced 1KB feat2 rows.
// ---------------------------------------------------------------------------
__global__ __launch_bounds__(1024, 8) void knn_gather_kernel(
    const float* __restrict__ xyz1, const float* __restrict__ xyz2,
    const float* __restrict__ feat2, ushort* __restrict__ interpB)
{
    __shared__ float4 sp[SS];                     // 32 KB
    __shared__ int   sIdx[128][3];
    __shared__ float sW[128][3];

    const int tid   = threadIdx.x;
    const int b     = blockIdx.x & 7;             // XCD-aligned batch
    const int chunk = blockIdx.x >> 3;            // 0..63
    const int qbase = chunk << 7;                 // 128 queries per block

    const float* x2 = xyz2 + (size_t)b * SS * 3;
    for (int i = tid; i < SS; i += 1024) {
        float x = x2[i*3+0], y = x2[i*3+1], z = x2[i*3+2];
        sp[i] = make_float4(-2.f*x, -2.f*y, -2.f*z, x*x + y*y + z*z);
    }
    __syncthreads();

    const int g = tid >> 4;                       // 0..63 (query pair)
    const int l = tid & 15;                       // lane within query
    const int qa = qbase + g * 2;

    const float* qp = xyz1 + ((size_t)b * NN + qa) * 3;
    float px[2] = {qp[0], qp[3]};
    float py[2] = {qp[1], qp[4]};
    float pz[2] = {qp[2], qp[5]};

    // ---------------- pass 1: top-3 values, branchless ----------------
    float c0[2], c1[2], c2[2];
#pragma unroll
    for (int qi = 0; qi < 2; ++qi) { c0[qi] = c1[qi] = c2[qi] = 1e30f; }

    for (int jj = 0; jj < 128; jj += 4) {
        float4 P[4];
#pragma unroll
        for (int u = 0; u < 4; ++u) P[u] = sp[((jj + u) << 4) + l];
#pragma unroll
        for (int u = 0; u < 4; ++u) {
#pragma unroll
            for (int qi = 0; qi < 2; ++qi) {
                float f = fmaf(px[qi], P[u].x,
                          fmaf(py[qi], P[u].y,
                          fmaf(pz[qi], P[u].z, P[u].w)));
                c2[qi] = med3(f, c1[qi], c2[qi]);
                c1[qi] = med3(f, c0[qi], c1[qi]);
                c0[qi] = fminf(f, c0[qi]);
            }
        }
    }

    // value-merge across the 16-lane group (multiset union top-3)
#pragma unroll
    for (int m = 1; m <= 8; m <<= 1) {
#pragma unroll
        for (int qi = 0; qi < 2; ++qi) {
            float b0 = __shfl_xor(c0[qi], m);
            float b1 = __shfl_xor(c1[qi], m);
            float b2 = __shfl_xor(c2[qi], m);
            float bv[3] = {b0, b1, b2};
#pragma unroll
            for (int e = 0; e < 3; ++e) {
                float d = bv[e];
                c2[qi] = med3(d, c1[qi], c2[qi]);
                c1[qi] = med3(d, c0[qi], c1[qi]);
                c0[qi] = fminf(d, c0[qi]);
            }
        }
    }
    const float t0 = c2[0], t1 = c2[1];           // exact 3rd-smallest scores

    // ---------------- pass 2: index recovery (rare inserts) ----------------
    float e0[2], e1[2], e2[2];
    int   i0[2], i1[2], i2[2];
#pragma unroll
    for (int qi = 0; qi < 2; ++qi) {
        e0[qi] = e1[qi] = e2[qi] = 1e30f;
        i0[qi] = i1[qi] = i2[qi] = 0x3fffffff;
    }

    for (int jj = 0; jj < 128; jj += 4) {
        float4 P[4];
#pragma unroll
        for (int u = 0; u < 4; ++u) P[u] = sp[((jj + u) << 4) + l];
#pragma unroll
        for (int u = 0; u < 4; ++u) {
            const int s = ((jj + u) << 4) + l;
#pragma unroll
            for (int qi = 0; qi < 2; ++qi) {
                float f = fmaf(px[qi], P[u].x,
                          fmaf(py[qi], P[u].y,
                          fmaf(pz[qi], P[u].z, P[u].w)));
                float tq = qi ? t1 : t0;
                if (f <= tq) {                     // ~3 hits per query total
                    bool lt2 = (f < e2[qi]) || (f == e2[qi] && s < i2[qi]);
                    if (lt2) {
                        bool lt1 = (f < e1[qi]) || (f == e1[qi] && s < i1[qi]);
                        bool lt0 = (f < e0[qi]) || (f == e0[qi] && s < i0[qi]);
                        e2[qi] = lt1 ? e1[qi] : f;  i2[qi] = lt1 ? i1[qi] : s;
                        e1[qi] = lt0 ? e0[qi] : (lt1 ? f : e1[qi]);
                        i1[qi] = lt0 ? i0[qi] : (lt1 ? s : i1[qi]);
                        e0[qi] = lt0 ? f : e0[qi];  i0[qi] = lt0 ? s : i0[qi];
                    }
                }
            }
        }
    }

    // lex merge across the 16-lane group
#pragma unroll
    for (int m = 1; m <= 8; m <<= 1) {
#pragma unroll
        for (int qi = 0; qi < 2; ++qi) {
            float ob0 = __shfl_xor(e0[qi], m), ob1 = __shfl_xor(e1[qi], m), ob2 = __shfl_xor(e2[qi], m);
            int   oj0 = __shfl_xor(i0[qi], m), oj1 = __shfl_xor(i1[qi], m), oj2 = __shfl_xor(i2[qi], m);
            float dv[3] = {ob0, ob1, ob2}; int iv[3] = {oj0, oj1, oj2};
#pragma unroll
            for (int e = 0; e < 3; ++e) {
                float d = dv[e]; int s = iv[e];
                bool lt2 = (d < e2[qi]) || (d == e2[qi] && s < i2[qi]);
                if (lt2) {
                    bool lt1 = (d < e1[qi]) || (d == e1[qi] && s < i1[qi]);
                    bool lt0 = (d < e0[qi]) || (d == e0[qi] && s < i0[qi]);
                    e2[qi] = lt1 ? e1[qi] : d;  i2[qi] = lt1 ? i1[qi] : s;
                    e1[qi] = lt0 ? e0[qi] : (lt1 ? d : e1[qi]);
                    i1[qi] = lt0 ? i0[qi] : (lt1 ? s : i1[qi]);
                    e0[qi] = lt0 ? d : e0[qi];  i0[qi] = lt0 ? s : i0[qi];
                }
            }
        }
    }

    if (l == 0) {
#pragma unroll
        for (int qi = 0; qi < 2; ++qi) {
            float nx = px[qi], ny = py[qi], nz = pz[qi];
            float n1 = nx*nx + ny*ny + nz*nz;
            float d0 = sqrtf(fmaxf(n1 + e0[qi], 0.f));
            float d1 = sqrtf(fmaxf(n1 + e1[qi], 0.f));
            float d2s = sqrtf(fmaxf(n1 + e2[qi], 0.f));
            float w0 = 1.f / fmaxf(d0, 1e-10f);
            float w1 = 1.f / fmaxf(d1, 1e-10f);
            float w2 = 1.f / fmaxf(d2s, 1e-10f);
            float wsum = w0 + w1 + w2;
            int qq = g * 2 + qi;
            sIdx[qq][0] = i0[qi]; sIdx[qq][1] = i1[qi]; sIdx[qq][2] = i2[qi];
            sW[qq][0] = w0 / wsum; sW[qq][1] = w1 / wsum; sW[qq][2] = w2 / wsum;
        }
    }
    __syncthreads();

    // gather phase: wave wid handles queries wid, wid+16, ... (coalesced rows)
    const int wid = tid >> 6, lane = tid & 63;
    for (int qq = wid; qq < 128; qq += 16) {
        int a0 = sIdx[qq][0], a1 = sIdx[qq][1], a2 = sIdx[qq][2];
        float w0 = sW[qq][0], w1 = sW[qq][1], w2 = sW[qq][2];
        const float4* r0 = (const float4*)(feat2 + ((size_t)b * SS + a0) * C2C);
        const float4* r1 = (const float4*)(feat2 + ((size_t)b * SS + a1) * C2C);
        const float4* r2 = (const float4*)(feat2 + ((size_t)b * SS + a2) * C2C);
        float4 v0 = r0[lane], v1 = r1[lane], v2 = r2[lane];
        ushort4 o;
        o.x = f2bf(w0*v0.x + w1*v1.x + w2*v2.x);
        o.y = f2bf(w0*v0.y + w1*v1.y + w2*v2.y);
        o.z = f2bf(w0*v0.z + w1*v1.z + w2*v2.z);
        o.w = f2bf(w0*v0.w + w1*v1.w + w2*v2.w);
        *(ushort4*)(interpB + ((size_t)b * NN + qbase + qq) * C2C + lane * 4) = o;
    }
}

// ---------------------------------------------------------------------------
// Both weight transposes (W1: 384x256, W2: 256x256) in one launch.
// ---------------------------------------------------------------------------
__global__ __launch_bounds__(256) void transpose_cvt_both_kernel(
    const float* __restrict__ W1, ushort* __restrict__ W1t,
    const float* __restrict__ W2, ushort* __restrict__ W2t)
{
    int idx = blockIdx.x * 256 + threadIdx.x;
    const int n1 = KIN * OUTC;                    // 98304
    if (idx < n1) {
        int n = idx / KIN, k = idx - n * KIN;
        W1t[idx] = f2bf(W1[(size_t)k * OUTC + n]);
    } else {
        int j = idx - n1;
        if (j < OUTC * OUTC) {
            int n = j / OUTC, k = j - n * OUTC;
            W2t[j] = f2bf(W2[(size_t)k * OUTC + n]);
        }
    }
}

// ---------------------------------------------------------------------------
// FUSED two-layer MFMA GEMM, v3 = r11-verified structure + phase-1 dbuf:
//   out = relu(relu(A@W1t^T + b1)@W2t^T + b2), H in LDS only.
// r12 lesson: B DIRECT from global regressed (stride-768B frag reads double
// W traffic, latency lands on the MFMA chain) -> B stays LDS-staged.
// NEW: phase-1 staging double-buffered, buffers ALIASED inside the 64KB H
// pool (dead until transition): buf = sA(8KB)+sB(16KB), x2 = 48KB <= 64KB.
// Loop: barrier -> issue stage(k+1 -> buf^1) -> compute(buf). ONE barrier
// per K-step (was 2); staging latency hidden under the 16 MFMAs.
// Phase 2 / transition identical to r11 (sB2-staged W2t, measured-good).
// LDS: 64KB pool + 16KB sB2 = 80KB -> 2 blocks/CU unchanged.
// C/D mapping (verified r1+): col = lane&15, row = (lane>>4)*4 + reg.
// ---------------------------------------------------------------------------
#define GBM 128
#define GBN 256
#define GBK 32

__device__ __forceinline__ void gld_lds16(const void* g, void* l) {
    __builtin_amdgcn_global_load_lds(
        (const __attribute__((address_space(1))) void*)g,
        (__attribute__((address_space(3))) void*)l, 16, 0, 0);
}

__global__ __launch_bounds__(512, 4) void gemm_fused(
    const float* __restrict__ feat1,
    const ushort* __restrict__ interpB,
    const ushort* __restrict__ W1t, const float* __restrict__ b1,
    const ushort* __restrict__ W2t, const float* __restrict__ b2,
    float* __restrict__ out)
{
    __shared__ ushort pool[GBM * 256];   // 64 KB: phase1 dbuf (2x24KB); then H
    __shared__ ushort sB2[GBN * GBK];    // 16 KB: phase2 W2t K-slice

    const int tid  = threadIdx.x;
    const int lane = tid & 63;
    const int wid  = tid >> 6;           // 0..7
    const int m0   = blockIdx.x * GBM;
    const int wr   = wid >> 2;           // 0..1
    const int wc   = wid & 3;            // 0..3

    const int rsub = lane >> 2;                    // 0..15 (row in 16-row chunk)
    const int slot = lane & 3;                     // 0..3  (8-ushort slot)
    const int csub = slot * 8;                     // linear LDS slot offset
    const int usw  = (slot ^ (rsub & 3)) * 8;      // swizzled SOURCE slot offset

    const int kgrp = (lane >> 4) * 8;
    const int rl   = lane & 15;
    const int ksw  = kgrp ^ ((rl & 3) << 3);       // swizzled read slot
    const int cl   = lane & 15;
    const int rgrp = (lane >> 4) * 4;

    // stage one K-step of A (8 chunks) + W1t (16 chunks) into buffer `buf`.
    // 24 chunks over 8 waves = 3 per wave, wave-uniform cid.
    auto stageAB = [&](int k0, int buf) {
        ushort* sAb = pool + buf * 12288;          // 8KB A
        ushort* sBb = sAb + 4096;                  // 16KB B
#pragma unroll
        for (int c = 0; c < 3; ++c) {
            const int cid = wid * 3 + c;           // 0..23
            if (cid < 8) {
                const int r = m0 + cid * 16 + rsub;
                if (k0 < C1C) {
                    const float* src = feat1 + (size_t)r * C1C + k0 + usw;
                    float4 u = ((const float4*)src)[0];
                    float4 v = ((const float4*)src)[1];
                    ushortx8 t;
                    t[0] = f2bf(u.x); t[1] = f2bf(u.y); t[2] = f2bf(u.z); t[3] = f2bf(u.w);
                    t[4] = f2bf(v.x); t[5] = f2bf(v.y); t[6] = f2bf(v.z); t[7] = f2bf(v.w);
                    *(ushortx8*)&sAb[cid * 512 + rsub * 32 + csub] = t;
                } else {
                    gld_lds16(interpB + (size_t)r * C2C + (k0 - C1C) + usw, &sAb[cid * 512]);
                }
            } else {
                const int bi = cid - 8;
                const int r = bi * 16 + rsub;
                gld_lds16(W1t + (size_t)r * KIN + k0 + usw, &sBb[bi * 512]);
            }
        }
    };

    // ---------------- phase 1: acc1 = A @ W1t^T (double-buffered) ----------
    f32x4 acc1[4][4];
#pragma unroll
    for (int i = 0; i < 4; ++i)
#pragma unroll
        for (int j = 0; j < 4; ++j) acc1[i][j] = (f32x4){0.f, 0.f, 0.f, 0.f};

    int cur = 0;
    stageAB(0, 0);
    for (int k0 = 0; k0 < KIN; k0 += GBK) {
        __syncthreads();                 // stage(k0->cur) done; prev reads done
        if (k0 + GBK < KIN) stageAB(k0 + GBK, cur ^ 1);

        const ushort* sAb = pool + cur * 12288;
        const ushort* sBb = sAb + 4096;
        short8 af[4], bf[4];
#pragma unroll
        for (int i = 0; i < 4; ++i) {
            af[i] = *(const short8*)&sAb[(wr * 64 + i * 16 + rl) * GBK + ksw];
            bf[i] = *(const short8*)&sBb[(wc * 64 + i * 16 + rl) * GBK + ksw];
        }
#pragma unroll
        for (int i = 0; i < 4; ++i)
#pragma unroll
            for (int j = 0; j < 4; ++j)
                acc1[i][j] = __builtin_amdgcn_mfma_f32_16x16x32_bf16(
                    af[i], bf[j], acc1[i][j], 0, 0, 0);
        cur ^= 1;
    }
    __syncthreads();                     // all phase-1 LDS reads done (pool reuse)

    // ---------------- transition: H = relu(acc1+b1) -> LDS (bf16) ----------
    // stage first W2t K-slice while writing H (latency overlap)
#pragma unroll
    for (int c = 0; c < 2; ++c) {
        const int cid = wid * 2 + c;                   // 0..15
        const int r = cid * 16 + rsub;
        gld_lds16(W2t + (size_t)r * OUTC + 0 + usw, &sB2[cid * 512]);
    }

#pragma unroll
    for (int j = 0; j < 4; ++j) {
        const int c = wc * 64 + j * 16 + cl;
        const float bv = b1[c];
        const int u = c >> 3, sub = c & 7;
#pragma unroll
        for (int i = 0; i < 4; ++i) {
#pragma unroll
            for (int rr = 0; rr < 4; ++rr) {
                const int r = wr * 64 + i * 16 + rgrp + rr;
                const float v = fmaxf(acc1[i][j][rr] + bv, 0.f);
                pool[r * 256 + ((u ^ (r & 31)) << 3) + sub] = f2bf(v);
            }
        }
    }
    __syncthreads();   // H complete + sB2(k0=0) staged (vmcnt drained by barrier)

    // ---------------- phase 2: out = relu(H @ W2t^T + b2) ------------------
    f32x4 acc2[4][4];
#pragma unroll
    for (int i = 0; i < 4; ++i)
#pragma unroll
        for (int j = 0; j < 4; ++j) acc2[i][j] = (f32x4){0.f, 0.f, 0.f, 0.f};

    for (int k0 = 0; k0 < OUTC; k0 += GBK) {
        short8 af[4], bf[4];
        const int ub = (k0 >> 3) + (lane >> 4);        // H unit index 0..31
#pragma unroll
        for (int i = 0; i < 4; ++i) {
            const int r = wr * 64 + i * 16 + rl;
            af[i] = *(const short8*)&pool[r * 256 + ((ub ^ (r & 31)) << 3)];
            bf[i] = *(const short8*)&sB2[(wc * 64 + i * 16 + rl) * GBK + ksw];
        }
#pragma unroll
        for (int i = 0; i < 4; ++i)
#pragma unroll
            for (int j = 0; j < 4; ++j)
                acc2[i][j] = __builtin_amdgcn_mfma_f32_16x16x32_bf16(
                    af[i], bf[j], acc2[i][j], 0, 0, 0);

        const int kn = k0 + GBK;
        __syncthreads();                               // sB2 reads complete
        if (kn < OUTC) {
#pragma unroll
            for (int c = 0; c < 2; ++c) {
                const int cid = wid * 2 + c;
                const int r = cid * 16 + rsub;
                gld_lds16(W2t + (size_t)r * OUTC + kn + usw, &sB2[cid * 512]);
            }
            __syncthreads();
        }
    }

    // ---------------- epilogue: bias + relu -> f32 out ---------------------
#pragma unroll
    for (int j = 0; j < 4; ++j) {
        const int col = wc * 64 + j * 16 + cl;
        const float bv = b2[col];
#pragma unroll
        for (int i = 0; i < 4; ++i) {
            const int rowb = m0 + wr * 64 + i * 16 + rgrp;
#pragma unroll
            for (int rr = 0; rr < 4; ++rr) {
                out[(size_t)(rowb + rr) * OUTC + col] =
                    fmaxf(acc2[i][j][rr] + bv, 0.f);
            }
        }
    }
}

// ---------------------------------------------------------------------------
// ws layout (bytes): interpB 33.5M @0 | W1t @33554432 | W2t @33751040
// ---------------------------------------------------------------------------
extern "C" void kernel_launch(void* const* d_in, const int* in_sizes, int n_in,
                              void* d_out, int out_size, void* d_ws, size_t ws_size,
                              hipStream_t stream) {
    const float* xyz1  = (const float*)d_in[0];
    const float* xyz2  = (const float*)d_in[1];
    const float* feat1 = (const float*)d_in[2];
    const float* feat2 = (const float*)d_in[3];
    const float* W1    = (const float*)d_in[4];
    const float* b1    = (const float*)d_in[5];
    const float* W2    = (const float*)d_in[6];
    const float* b2    = (const float*)d_in[7];
    float* out = (float*)d_out;

    char* ws = (char*)d_ws;
    ushort* interpB = (ushort*)(ws);
    ushort* W1t     = (ushort*)(ws + 33554432);
    ushort* W2t     = (ushort*)(ws + 33751040);

    const int M = BB * NN;  // 65536

    transpose_cvt_both_kernel<<<(KIN * OUTC + OUTC * OUTC + 255) / 256, 256, 0, stream>>>(
        W1, W1t, W2, W2t);

    knn_gather_kernel<<<512, 1024, 0, stream>>>(xyz1, xyz2, feat2, interpB);

    gemm_fused<<<M / GBM, 512, 0, stream>>>(feat1, interpB, W1t, b1, W2t, b2, out);
}